// Round 1
// baseline (500.467 us; speedup 1.0000x reference)
//
#include <hip/hip_runtime.h>

typedef float        f32x4  __attribute__((ext_vector_type(4)));
typedef __bf16       bf16x8 __attribute__((ext_vector_type(8)));
typedef __bf16       bf16x4 __attribute__((ext_vector_type(4)));

#define NN   8192
#define IND  256
#define OUTD 128
#define NB   144    // part cols: 0..127 = num, 128 = den, 129..143 unused pad
#define KSPLIT 8
#define KRANGE 1024 // 8192 / KSPLIT
#define KCHUNK 128

__device__ __forceinline__ bf16x8 cvt2(f32x4 a, f32x4 b) {
  bf16x8 r;
  r[0]=(__bf16)a[0]; r[1]=(__bf16)a[1]; r[2]=(__bf16)a[2]; r[3]=(__bf16)a[3];
  r[4]=(__bf16)b[0]; r[5]=(__bf16)b[1]; r[6]=(__bf16)b[2]; r[7]=(__bf16)b[3];
  return r;
}

// K1 (fused old k1+k2): per wave computes 16 rows x 128 cols of Wh = X@W^T via MFMA,
// reduces e = relu(Wh).a_w (butterfly allreduce leaves e in ALL lanes), then writes
// B^T directly: Bt[n][j] = exp(e_j)*Wh[j][n] (n<128), Bt[128][j] = exp(e_j),
// Bt[129..143][j] = 0.  Wh never touches HBM.
__global__ __launch_bounds__(128) void k1_bt(const float* __restrict__ X,
                                             const float* __restrict__ W,
                                             const float* __restrict__ aw,
                                             __bf16* __restrict__ Bt) {
  const int lane = threadIdx.x & 63;
  const int wave = threadIdx.x >> 6;
  const int nlo  = lane & 15;
  const int quad = lane >> 4;
  const int rowBase = blockIdx.x * 32 + wave * 16;

  const float* xp = X + (size_t)(rowBase + nlo) * IND + quad * 8;
  f32x4 acc[8];
#pragma unroll
  for (int nt = 0; nt < 8; ++nt) acc[nt] = f32x4{0.f, 0.f, 0.f, 0.f};

#pragma unroll
  for (int kb = 0; kb < IND; kb += 32) {
    f32x4 a0 = *(const f32x4*)(xp + kb);
    f32x4 a1 = *(const f32x4*)(xp + kb + 4);
    bf16x8 af = cvt2(a0, a1);
#pragma unroll
    for (int nt = 0; nt < 8; ++nt) {
      const float* wp = W + (size_t)(nt * 16 + nlo) * IND + kb + quad * 8;
      f32x4 b0 = *(const f32x4*)wp;
      f32x4 b1 = *(const f32x4*)(wp + 4);
      acc[nt] = __builtin_amdgcn_mfma_f32_16x16x32_bf16(af, cvt2(b0, b1), acc[nt], 0, 0, 0);
    }
  }

  // e = relu(Wh) . a_w for this lane's 4 rows (r0..r0+3)
  float p0 = 0.f, p1 = 0.f, p2 = 0.f, p3 = 0.f;
#pragma unroll
  for (int nt = 0; nt < 8; ++nt) {
    const float awc = aw[nt * 16 + nlo];
    p0 += fmaxf(acc[nt][0], 0.f) * awc;
    p1 += fmaxf(acc[nt][1], 0.f) * awc;
    p2 += fmaxf(acc[nt][2], 0.f) * awc;
    p3 += fmaxf(acc[nt][3], 0.f) * awc;
  }
#pragma unroll
  for (int off = 8; off; off >>= 1) {   // butterfly = allreduce within 16-lane group
    p0 += __shfl_xor(p0, off, 64);
    p1 += __shfl_xor(p1, off, 64);
    p2 += __shfl_xor(p2, off, 64);
    p3 += __shfl_xor(p3, off, 64);
  }
  const float w0 = expf(p0), w1 = expf(p1), w2 = expf(p2), w3 = expf(p3);
  const int r0 = rowBase + quad * 4;

#pragma unroll
  for (int nt = 0; nt < 8; ++nt) {
    bf16x4 o;
    o[0] = (__bf16)(acc[nt][0] * w0);
    o[1] = (__bf16)(acc[nt][1] * w1);
    o[2] = (__bf16)(acc[nt][2] * w2);
    o[3] = (__bf16)(acc[nt][3] * w3);
    *(bf16x4*)(Bt + (size_t)(nt * 16 + nlo) * NN + r0) = o;   // 8B packed store
  }
  if (nlo == 0) {
    bf16x4 ow;
    ow[0] = (__bf16)w0; ow[1] = (__bf16)w1; ow[2] = (__bf16)w2; ow[3] = (__bf16)w3;
    *(bf16x4*)(Bt + (size_t)OUTD * NN + r0) = ow;             // denominator row
  }
  // zero pad rows 129..143 for this block's 32-col j slice
  {
    const int t = threadIdx.x;
    if (t < 120) {
      const int row = 129 + (t >> 3);
      const int cg  = (t & 7) * 4;
      bf16x4 z;
      z[0] = (__bf16)0.f; z[1] = (__bf16)0.f; z[2] = (__bf16)0.f; z[3] = (__bf16)0.f;
      *(bf16x4*)(Bt + (size_t)row * NN + blockIdx.x * 32 + cg) = z;
    }
  }
}

// K3a: part[slice][8192 x 144] = Adj(->bf16) @ B over slice's 1024-k range.
// No LDS, no barriers: B fragments load straight from global (slice tile = 288 KB,
// L2-resident, all 128 row-blocks of a slice share it); A streamed nontemporal.
__global__ __launch_bounds__(256, 4) void k3_partial(const float* __restrict__ Adj,
                                                     const __bf16* __restrict__ Bt,
                                                     float* __restrict__ part) {
  const int lane = threadIdx.x & 63;
  const int wave = threadIdx.x >> 6;
  const int nlo  = lane & 15;
  const int quad = lane >> 4;
  const int rowW = blockIdx.x * 64 + wave * 16;   // wave's 16 rows
  const int k0   = blockIdx.y * KRANGE;

  f32x4 acc[9];
#pragma unroll
  for (int nt = 0; nt < 9; ++nt) acc[nt] = f32x4{0.f, 0.f, 0.f, 0.f};

  const float*  ap = Adj + (size_t)(rowW + nlo) * NN + quad * 8 + k0;
  const __bf16* bp = Bt  + (size_t)nlo * NN + quad * 8 + k0;

  for (int c = 0; c < KRANGE / KCHUNK; ++c) {
    f32x4 areg[8];
#pragma unroll
    for (int s = 0; s < 4; ++s) {
      areg[2 * s]     = __builtin_nontemporal_load((const f32x4*)(ap + c * KCHUNK + s * 32));
      areg[2 * s + 1] = __builtin_nontemporal_load((const f32x4*)(ap + c * KCHUNK + s * 32 + 4));
    }
#pragma unroll
    for (int s = 0; s < 4; ++s) {
      bf16x8 af = cvt2(areg[2 * s], areg[2 * s + 1]);
#pragma unroll
      for (int nt = 0; nt < 9; ++nt) {
        bf16x8 bf = *(const bf16x8*)(bp + (size_t)(nt * 16) * NN + c * KCHUNK + s * 32);
        acc[nt] = __builtin_amdgcn_mfma_f32_16x16x32_bf16(af, bf, acc[nt], 0, 0, 0);
      }
    }
  }

  float* pbase = part + ((size_t)blockIdx.y * NN + rowW) * NB;
#pragma unroll
  for (int nt = 0; nt < 9; ++nt)
#pragma unroll
    for (int rg = 0; rg < 4; ++rg)
      pbase[(size_t)(quad * 4 + rg) * NB + nt * 16 + nlo] = acc[nt][rg];
}

// K3b: out[row][col] = relu( sum_s part[s][row][col] / sum_s part[s][row][128] )
__global__ __launch_bounds__(256) void k3_reduce(const float* __restrict__ part,
                                                 float* __restrict__ out) {
  const int col = threadIdx.x & 127;
  const int row = blockIdx.x * 2 + (threadIdx.x >> 7);
  float num = 0.f, den = 0.f;
#pragma unroll
  for (int s = 0; s < KSPLIT; ++s) {
    const size_t base = ((size_t)s * NN + row) * NB;
    num += part[base + col];
    den += part[base + 128];
  }
  out[(size_t)row * OUTD + col] = fmaxf(num / den, 0.f);
}

extern "C" void kernel_launch(void* const* d_in, const int* in_sizes, int n_in,
                              void* d_out, int out_size, void* d_ws, size_t ws_size,
                              hipStream_t stream) {
  const float* X  = (const float*)d_in[0];
  const float* A  = (const float*)d_in[1];
  const float* W  = (const float*)d_in[2];
  const float* aw = (const float*)d_in[3];
  float* out = (float*)d_out;

  char* ws = (char*)d_ws;
  __bf16* Bt   = (__bf16*)ws;                   // 144*8192*2  = 2.25 MiB
  float*  part = (float*)(ws + 4194304);        // 8*8192*144*4 = 37.75 MiB

  k1_bt<<<256, 128, 0, stream>>>(X, W, aw, Bt);
  k3_partial<<<dim3(128, KSPLIT), 256, 0, stream>>>(A, Bt, part);
  k3_reduce<<<4096, 256, 0, stream>>>(part, out);
}

// Round 3
// 415.128 us; speedup vs baseline: 1.2056x; 1.2056x over previous
//
#include <hip/hip_runtime.h>

typedef float        f32x4  __attribute__((ext_vector_type(4)));
typedef __bf16       bf16x8 __attribute__((ext_vector_type(8)));
typedef __bf16       bf16x4 __attribute__((ext_vector_type(4)));
typedef unsigned int u32x4  __attribute__((ext_vector_type(4)));

#define NN   8192
#define IND  256
#define OUTD 128
#define NB   144    // part cols: 0..127 = num, 128 = den, 129..143 never read
#define KSPLIT 8
#define KRANGE 1024 // 8192 / KSPLIT
#define KCHUNK 128
#define BSTRIDE 136 // 128 + 8 bf16 pad: 272 B rows -> 2-way LDS aliasing only (free)

__device__ __forceinline__ bf16x8 cvt2(f32x4 a, f32x4 b) {
  bf16x8 r;
  r[0]=(__bf16)a[0]; r[1]=(__bf16)a[1]; r[2]=(__bf16)a[2]; r[3]=(__bf16)a[3];
  r[4]=(__bf16)b[0]; r[5]=(__bf16)b[1]; r[6]=(__bf16)b[2]; r[7]=(__bf16)b[3];
  return r;
}

// K1: Wh = X @ W^T [8192,128] fp32; e[j] = relu(Wh[j]).a_w
// 512 blocks x 256 thr. Block = 16 rows. Wave w covers k in [w*64,(w+1)*64):
// 4-way K-split -> 2048 waves (2/SIMD) instead of 512 (0.5/SIMD).
// Partial accs merged through LDS; coalesced Wh/ev writes.
__global__ __launch_bounds__(256) void k1_wh_e(const float* __restrict__ X,
                                               const float* __restrict__ W,
                                               const float* __restrict__ aw,
                                               float* __restrict__ Wh,
                                               float* __restrict__ ev) {
  __shared__ float red[4][16][128];   // 32 KB
  const int tid  = threadIdx.x;
  const int lane = tid & 63;
  const int wave = tid >> 6;
  const int nlo  = lane & 15;
  const int quad = lane >> 4;
  const int rowBase = blockIdx.x * 16;

  const float* xp = X + (size_t)(rowBase + nlo) * IND + wave * 64 + quad * 8;
  f32x4 acc[8];
#pragma unroll
  for (int nt = 0; nt < 8; ++nt) acc[nt] = f32x4{0.f, 0.f, 0.f, 0.f};

#pragma unroll
  for (int kb = 0; kb < 64; kb += 32) {
    f32x4 a0 = *(const f32x4*)(xp + kb);
    f32x4 a1 = *(const f32x4*)(xp + kb + 4);
    bf16x8 af = cvt2(a0, a1);
#pragma unroll
    for (int nt = 0; nt < 8; ++nt) {
      const float* wp = W + (size_t)(nt * 16 + nlo) * IND + wave * 64 + kb + quad * 8;
      f32x4 b0 = *(const f32x4*)wp;
      f32x4 b1 = *(const f32x4*)(wp + 4);
      acc[nt] = __builtin_amdgcn_mfma_f32_16x16x32_bf16(af, cvt2(b0, b1), acc[nt], 0, 0, 0);
    }
  }
  // scatter partial C to LDS: row (quad*4+rg), col (nt*16+nlo)
#pragma unroll
  for (int nt = 0; nt < 8; ++nt)
#pragma unroll
    for (int rg = 0; rg < 4; ++rg)
      red[wave][quad * 4 + rg][nt * 16 + nlo] = acc[nt][rg];
  __syncthreads();

  // merge: thread t owns row r = t>>4, cols c0..c0+7
  const int r  = tid >> 4;
  const int c0 = (tid & 15) * 8;
  f32x4 vlo = *(const f32x4*)&red[0][r][c0];
  f32x4 vhi = *(const f32x4*)&red[0][r][c0 + 4];
#pragma unroll
  for (int w = 1; w < 4; ++w) {
    vlo += *(const f32x4*)&red[w][r][c0];
    vhi += *(const f32x4*)&red[w][r][c0 + 4];
  }
  *(f32x4*)(Wh + (size_t)(rowBase + r) * OUTD + c0)     = vlo;
  *(f32x4*)(Wh + (size_t)(rowBase + r) * OUTD + c0 + 4) = vhi;

  float pa = 0.f;
#pragma unroll
  for (int j = 0; j < 4; ++j) {
    pa += fmaxf(vlo[j], 0.f) * aw[c0 + j];
    pa += fmaxf(vhi[j], 0.f) * aw[c0 + 4 + j];
  }
#pragma unroll
  for (int off = 8; off; off >>= 1) pa += __shfl_xor(pa, off, 64);  // 16-lane groups
  if ((tid & 15) == 0) ev[rowBase + r] = pa;
}

// K2: B^T [NB][NN] bf16: row n<128: w_j*Wh[j][n]; row 128: w_j; rows 129..143: 0
__global__ __launch_bounds__(256) void k2_bt(const float* __restrict__ Wh,
                                             const float* __restrict__ ev,
                                             __bf16* __restrict__ Bt) {
  const int j = blockIdx.x * 256 + threadIdx.x;
  const float w = expf(ev[j]);
  const int n0 = blockIdx.y * 18;
#pragma unroll
  for (int i = 0; i < 18; ++i) {
    const int n = n0 + i;
    float v = 0.f;
    if (n < OUTD) v = w * Wh[(size_t)j * OUTD + n];
    else if (n == OUTD) v = w;
    Bt[(size_t)n * NN + j] = (__bf16)v;
  }
}

// K3a: part[slice][8192 x NB] = Adj(->bf16) @ B over slice's 1024-k range.
// LDS-staged B (proven necessary, round 1). 2-phase register double-buffer:
// chunk c+1's global loads issue BEFORE chunk c's MFMAs, so the vmcnt(0)
// drain at the trailing __syncthreads lands after ~400cy of MFMA cover.
__global__ __launch_bounds__(256, 2) void k3_partial(const float* __restrict__ Adj,
                                                     const __bf16* __restrict__ Bt,
                                                     float* __restrict__ part) {
  __shared__ unsigned short bt[NB * BSTRIDE];  // 38.25 KB
  const int tid  = threadIdx.x;
  const int lane = tid & 63;
  const int wave = tid >> 6;
  const int nlo  = lane & 15;
  const int quad = lane >> 4;
  const int rowW = blockIdx.x * 64 + wave * 16;
  const int k0   = blockIdx.y * KRANGE;

  const int brow = tid >> 4;        // 0..15
  const int bcol = (tid & 15) * 8;  // bf16 elems, 16B per thread

  f32x4 acc[9];
#pragma unroll
  for (int nt = 0; nt < 9; ++nt) acc[nt] = f32x4{0.f, 0.f, 0.f, 0.f};

  const float*  ap = Adj + (size_t)(rowW + nlo) * NN + quad * 8 + k0;
  const __bf16* bq = Bt + (size_t)brow * NN + k0 + bcol;

  // prologue: chunk 0 loads
  u32x4 bregA[9];
  f32x4 aregA[8];
#pragma unroll
  for (int rr = 0; rr < 9; ++rr)
    bregA[rr] = *(const u32x4*)(bq + (size_t)(rr * 16) * NN);
#pragma unroll
  for (int s = 0; s < 4; ++s) {
    aregA[2 * s]     = __builtin_nontemporal_load((const f32x4*)(ap + s * 32));
    aregA[2 * s + 1] = __builtin_nontemporal_load((const f32x4*)(ap + s * 32 + 4));
  }

  for (int c = 0; c < KRANGE / KCHUNK; ++c) {
    // stage B(c) into LDS (waits only on bregA arrival)
#pragma unroll
    for (int rr = 0; rr < 9; ++rr)
      *(u32x4*)(bt + (rr * 16 + brow) * BSTRIDE + bcol) = bregA[rr];
    __syncthreads();

    // issue chunk c+1 loads: in flight across the MFMA phase
    u32x4 bregB[9];
    f32x4 aregB[8];
    if (c < KRANGE / KCHUNK - 1) {
      const int kc1 = (c + 1) * KCHUNK;
#pragma unroll
      for (int rr = 0; rr < 9; ++rr)
        bregB[rr] = *(const u32x4*)(bq + (size_t)(rr * 16) * NN + kc1);
#pragma unroll
      for (int s = 0; s < 4; ++s) {
        aregB[2 * s]     = __builtin_nontemporal_load((const f32x4*)(ap + kc1 + s * 32));
        aregB[2 * s + 1] = __builtin_nontemporal_load((const f32x4*)(ap + kc1 + s * 32 + 4));
      }
    }

    // MFMA on chunk c
#pragma unroll
    for (int s = 0; s < 4; ++s) {
      bf16x8 af = cvt2(aregA[2 * s], aregA[2 * s + 1]);
      const unsigned short* bp = bt + s * 32 + quad * 8;
#pragma unroll
      for (int nt = 0; nt < 9; ++nt) {
        bf16x8 bf = *(const bf16x8*)(bp + (nt * 16 + nlo) * BSTRIDE);
        acc[nt] = __builtin_amdgcn_mfma_f32_16x16x32_bf16(af, bf, acc[nt], 0, 0, 0);
      }
    }
    __syncthreads();

    if (c < KRANGE / KCHUNK - 1) {
#pragma unroll
      for (int rr = 0; rr < 9; ++rr) bregA[rr] = bregB[rr];
#pragma unroll
      for (int s = 0; s < 8; ++s) aregA[s] = aregB[s];
    }
  }

  float* pbase = part + ((size_t)blockIdx.y * NN + rowW) * NB;
#pragma unroll
  for (int nt = 0; nt < 8; ++nt)
#pragma unroll
    for (int rg = 0; rg < 4; ++rg)
      pbase[(size_t)(quad * 4 + rg) * NB + nt * 16 + nlo] = acc[nt][rg];
  if (nlo == 0) {
#pragma unroll
    for (int rg = 0; rg < 4; ++rg)
      pbase[(size_t)(quad * 4 + rg) * NB + 128] = acc[8][rg];
  }
}

// K3b: out[row][col] = relu( sum_s part[s][row][col] / sum_s part[s][row][128] )
__global__ __launch_bounds__(256) void k3_reduce(const float* __restrict__ part,
                                                 float* __restrict__ out) {
  const int col = threadIdx.x & 127;
  const int row = blockIdx.x * 2 + (threadIdx.x >> 7);
  float num = 0.f, den = 0.f;
#pragma unroll
  for (int s = 0; s < KSPLIT; ++s) {
    const size_t base = ((size_t)s * NN + row) * NB;
    num += part[base + col];
    den += part[base + 128];
  }
  out[(size_t)row * OUTD + col] = fmaxf(num / den, 0.f);
}

extern "C" void kernel_launch(void* const* d_in, const int* in_sizes, int n_in,
                              void* d_out, int out_size, void* d_ws, size_t ws_size,
                              hipStream_t stream) {
  const float* X  = (const float*)d_in[0];
  const float* A  = (const float*)d_in[1];
  const float* W  = (const float*)d_in[2];
  const float* aw = (const float*)d_in[3];
  float* out = (float*)d_out;

  char* ws = (char*)d_ws;
  float*  Wh   = (float*)ws;                    // 8192*128*4   = 4 MiB
  float*  ev   = (float*)(ws + 4194304);        // 8192*4       = 32 KiB
  __bf16* Bt   = (__bf16*)(ws + 4227072);       // 144*8192*2   = 2.25 MiB
  float*  part = (float*)(ws + 8388608);        // 8*8192*144*4 = 37.75 MiB

  k1_wh_e<<<512, 256, 0, stream>>>(X, W, aw, Wh, ev);
  k2_bt<<<dim3(32, 8), 256, 0, stream>>>(Wh, ev, Bt);
  k3_partial<<<dim3(128, KSPLIT), 256, 0, stream>>>(A, Bt, part);
  k3_reduce<<<4096, 256, 0, stream>>>(part, out);
}